// Round 4
// baseline (171.499 us; speedup 1.0000x reference)
//
#include <hip/hip_runtime.h>

// Problem constants (match reference)
#define BB   8
#define CC   1024
#define TT   4096
#define HH   16
#define KK   31
#define PADD 15

#define RPT  16                 // outputs per thread
#define NCH  12                 // float4 chunks per thread window (48 floats)

typedef float floatx4 __attribute__((ext_vector_type(4)));   // native vec for nt-store

// --- softmax over the 31 taps of each of the 16 heads ---
__global__ void lwconv_softmax_w(const float* __restrict__ w, float* __restrict__ wsm) {
    int h = threadIdx.x;
    if (h < HH) {
        float buf[KK];
        float m = -1e30f;
        #pragma unroll
        for (int k = 0; k < KK; ++k) { buf[k] = w[h * KK + k]; m = fmaxf(m, buf[k]); }
        float s = 0.f;
        #pragma unroll
        for (int k = 0; k < KK; ++k) { buf[k] = expf(buf[k] - m); s += buf[k]; }
        float inv = 1.f / s;
        #pragma unroll
        for (int k = 0; k < KK; ++k) wsm[h * KK + k] = buf[k] * inv;
    }
}

// --- main depthwise conv: one block = one row (b,c); thread = 16 consecutive t ---
// out[t] = bias + sum_k w[k] * x[t + k - 15]
// Thread window: element e = x[a - 16 + e], e in [0,48); out[a+r] uses e = r+1+k.
__global__ __launch_bounds__(256) void lwconv_main(const float* __restrict__ inp,
                                                   const float* __restrict__ wsm,
                                                   const float* __restrict__ bias,
                                                   float* __restrict__ out) {
    const int row  = blockIdx.x;         // b*C + ch, 0..8191
    const int ch   = row & (CC - 1);
    const int head = ch >> 6;            // 64 channels per head
    const int tid  = threadIdx.x;
    const int a    = tid << 4;           // first output index of this thread

    const float* rowp = inp + (size_t)row * TT;

    // Issue ALL window loads up front (12 outstanding global_load_dwordx4/wave).
    float4 vv[NCH];
    #pragma unroll
    for (int c = 0; c < NCH; ++c) {
        const int ge = a - 16 + 4 * c;   // global element index of chunk start
        if (ge >= 0 && ge <= TT - 4)
            vv[c] = *reinterpret_cast<const float4*>(rowp + ge);
        else
            vv[c] = make_float4(0.f, 0.f, 0.f, 0.f);   // whole chunk is padding
    }

    // block-uniform weights -> scalar regs
    float w[KK];
    #pragma unroll
    for (int k = 0; k < KK; ++k) w[k] = wsm[head * KK + k];
    const float bval = bias[head];

    // Fence: nothing below may be hoisted between the loads above.
    __builtin_amdgcn_sched_barrier(0);

    const float* xv = reinterpret_cast<const float*>(vv);   // compile-time indexed only

    float acc[RPT];
    #pragma unroll
    for (int r = 0; r < RPT; ++r) acc[r] = bval;

    #pragma unroll
    for (int k = 0; k < KK; ++k) {
        #pragma unroll
        for (int r = 0; r < RPT; ++r) {
            acc[r] = fmaf(xv[r + 1 + k], w[k], acc[r]);
        }
    }

    float* orow = out + (size_t)row * TT + a;
    #pragma unroll
    for (int c = 0; c < RPT / 4; ++c) {
        floatx4 o = { acc[4 * c], acc[4 * c + 1], acc[4 * c + 2], acc[4 * c + 3] };
        __builtin_nontemporal_store(o, reinterpret_cast<floatx4*>(orow + 4 * c));
    }
}

extern "C" void kernel_launch(void* const* d_in, const int* in_sizes, int n_in,
                              void* d_out, int out_size, void* d_ws, size_t ws_size,
                              hipStream_t stream) {
    const float* inp    = (const float*)d_in[0];   // (B, C, T) fp32
    const float* weight = (const float*)d_in[1];   // (H, 1, K) fp32
    const float* bias   = (const float*)d_in[2];   // (H,) fp32
    float* out = (float*)d_out;
    float* wsm = (float*)d_ws;                     // H*K softmaxed weights

    lwconv_softmax_w<<<1, 64, 0, stream>>>(weight, wsm);

    const int rows = BB * CC;                      // 8192 = one block per row
    lwconv_main<<<rows, 256, 0, stream>>>(inp, wsm, bias, out);
}

// Round 5
// 69.985 us; speedup vs baseline: 2.4505x; 2.4505x over previous
//
#include <hip/hip_runtime.h>

// Problem constants (match reference)
#define BB   8
#define CC   1024
#define TT   4096
#define HH   16
#define KK   31
#define PADD 15

#define RPT  16                  // outputs per thread (256 threads * 16 = 4096 = T)
#define NCH  12                  // ds_read_b128 per thread window (48 floats)
#define TILE_CHUNKS 1032         // logical float4 chunks per padded row: (4096+32)/4
// LDS layout: logical chunk q lives at physical byte 16*q + 16*(q>>2)
// (16B pad after every 64B -> 8 consecutive lanes cover all 8 bank-quads)
#define LDS_FLOAT4 ((TILE_CHUNKS * 16 + (TILE_CHUNKS / 4) * 16) / 16)   // 1290

// --- softmax over the 31 taps of each of the 16 heads ---
__global__ void lwconv_softmax_w(const float* __restrict__ w, float* __restrict__ wsm) {
    int h = threadIdx.x;
    if (h < HH) {
        float buf[KK];
        float m = -1e30f;
        #pragma unroll
        for (int k = 0; k < KK; ++k) { buf[k] = w[h * KK + k]; m = fmaxf(m, buf[k]); }
        float s = 0.f;
        #pragma unroll
        for (int k = 0; k < KK; ++k) { buf[k] = expf(buf[k] - m); s += buf[k]; }
        float inv = 1.f / s;
        #pragma unroll
        for (int k = 0; k < KK; ++k) wsm[h * KK + k] = buf[k] * inv;
    }
}

// --- main depthwise conv: one block = one row (b,c) ---
// out[t] = bias + sum_k w[k] * x[t + k - 15]
// LDS logical float index i corresponds to x[i - 16]; thread window
// logical chunks 4*tid .. 4*tid+11 (floats a-16 .. a+31), out[a+r] uses e=r+1+k.
__global__ __launch_bounds__(256) void lwconv_main(const float* __restrict__ inp,
                                                   const float* __restrict__ wsm,
                                                   const float* __restrict__ bias,
                                                   float* __restrict__ out) {
    __shared__ float4 s4[LDS_FLOAT4];
    char* sbase = reinterpret_cast<char*>(s4);

    const int row  = blockIdx.x;         // b*C + ch, 0..8191
    const int ch   = row & (CC - 1);
    const int head = ch >> 6;            // 64 channels per head
    const int tid  = threadIdx.x;
    const int a    = tid << 4;           // first output index of this thread

    const float* rowp = inp + (size_t)row * TT;

    // ---- stage padded row into LDS: independent coalesced float4 loads ----
    #pragma unroll
    for (int j = 0; j < 5; ++j) {
        const int q = tid + 256 * j;     // logical chunk
        if (q < TILE_CHUNKS) {
            const int ge = 4 * q - 16;   // global element index of chunk start
            float4 v;
            if (ge >= 0 && ge <= TT - 4)
                v = *reinterpret_cast<const float4*>(rowp + ge);
            else
                v = make_float4(0.f, 0.f, 0.f, 0.f);
            const int pb = 16 * q + ((q >> 2) << 4);   // physical byte (swizzled)
            *reinterpret_cast<float4*>(sbase + pb) = v;
        }
    }

    // block-uniform weights -> regs (overlaps with staging latency)
    float w[KK];
    #pragma unroll
    for (int k = 0; k < KK; ++k) w[k] = wsm[head * KK + k];
    const float bval = bias[head];

    __syncthreads();

    // ---- window: 12 ds_read_b128, padded layout (~2-way, free for b128) ----
    float xv[4 * NCH];
    const int base_b = 80 * tid;         // physical byte of logical chunk 4*tid
    #pragma unroll
    for (int c = 0; c < NCH; ++c) {
        const int pb = base_b + 16 * c + ((c >> 2) << 4);
        float4 v = *reinterpret_cast<const float4*>(sbase + pb);
        xv[4 * c + 0] = v.x; xv[4 * c + 1] = v.y;
        xv[4 * c + 2] = v.z; xv[4 * c + 3] = v.w;
    }

    float acc[RPT];
    #pragma unroll
    for (int r = 0; r < RPT; ++r) acc[r] = bval;

    #pragma unroll
    for (int k = 0; k < KK; ++k) {
        #pragma unroll
        for (int r = 0; r < RPT; ++r) {
            acc[r] = fmaf(xv[r + 1 + k], w[k], acc[r]);
        }
    }

    float* orow = out + (size_t)row * TT + a;
    #pragma unroll
    for (int c = 0; c < RPT / 4; ++c) {
        *reinterpret_cast<float4*>(orow + 4 * c) =
            make_float4(acc[4 * c], acc[4 * c + 1], acc[4 * c + 2], acc[4 * c + 3]);
    }
}

extern "C" void kernel_launch(void* const* d_in, const int* in_sizes, int n_in,
                              void* d_out, int out_size, void* d_ws, size_t ws_size,
                              hipStream_t stream) {
    const float* inp    = (const float*)d_in[0];   // (B, C, T) fp32
    const float* weight = (const float*)d_in[1];   // (H, 1, K) fp32
    const float* bias   = (const float*)d_in[2];   // (H,) fp32
    float* out = (float*)d_out;
    float* wsm = (float*)d_ws;                     // H*K softmaxed weights

    lwconv_softmax_w<<<1, 64, 0, stream>>>(weight, wsm);

    const int rows = BB * CC;                      // 8192 = one block per row
    lwconv_main<<<rows, 256, 0, stream>>>(inp, wsm, bias, out);
}

// Round 6
// 67.607 us; speedup vs baseline: 2.5367x; 1.0352x over previous
//
#include <hip/hip_runtime.h>

// Problem constants (match reference)
#define BB   8
#define CC   1024
#define TT   4096
#define HH   16
#define KK   31
#define PADD 15

#define RPT  16                  // outputs per thread (256 threads * 16 = 4096 = T)
#define NCH  12                  // ds_read_b128 per thread window (48 floats)
#define TILE_CHUNKS 1032         // logical float4 chunks per padded row: (4096+32)/4

// XOR swizzle: logical chunk q -> physical chunk p = q ^ ((q>>4)&7).
// Bijective (low 3 bits XORed with bits 4..6). Read (q=4*tid+c) and write
// (q=tid+256j) both spread each 16-lane group across all 8 bank-quads
// exactly twice -> 2 lanes/bank = conflict-free for ds_read/write_b128.
__device__ __forceinline__ int swz(int q) { return q ^ ((q >> 4) & 7); }

// --- fused kernel: one block = one row (b,c) ---
// out[t] = bias + sum_k w[k] * x[t + k - 15]
// LDS logical float index i corresponds to x[i - 16]; thread window =
// logical chunks 4*tid .. 4*tid+11 (floats a-16 .. a+31); out[a+r] uses e=r+1+k.
__global__ __launch_bounds__(256) void lwconv_main(const float* __restrict__ inp,
                                                   const float* __restrict__ weight,
                                                   const float* __restrict__ bias,
                                                   float* __restrict__ out) {
    __shared__ float4 s4[TILE_CHUNKS];

    const int row  = blockIdx.x;         // b*C + ch, 0..8191
    const int ch   = row & (CC - 1);
    const int head = ch >> 6;            // 64 channels per head
    const int tid  = threadIdx.x;
    const int a    = tid << 4;           // first output index of this thread

    const float* rowp = inp + (size_t)row * TT;

    // ---- stage padded row into LDS: independent coalesced float4 loads ----
    #pragma unroll
    for (int j = 0; j < 5; ++j) {
        const int q = tid + 256 * j;     // logical chunk
        if (q < TILE_CHUNKS) {
            const int ge = 4 * q - 16;   // global element index of chunk start
            float4 v;
            if (ge >= 0 && ge <= TT - 4)
                v = *reinterpret_cast<const float4*>(rowp + ge);
            else
                v = make_float4(0.f, 0.f, 0.f, 0.f);   // whole chunk is padding
            s4[swz(q)] = v;
        }
    }

    // ---- per-thread softmax of this head's 31 taps (wave-uniform s_loads;
    //      VALU hides under the staging latency) ----
    const float* wh = weight + head * KK;
    float w[KK];
    float m = -1e30f;
    #pragma unroll
    for (int k = 0; k < KK; ++k) { w[k] = wh[k]; m = fmaxf(m, w[k]); }
    float s = 0.f;
    #pragma unroll
    for (int k = 0; k < KK; ++k) { w[k] = __expf(w[k] - m); s += w[k]; }
    const float inv = 1.f / s;
    #pragma unroll
    for (int k = 0; k < KK; ++k) w[k] *= inv;
    const float bval = bias[head];

    __syncthreads();

    // ---- window: 12 ds_read_b128 from swizzled layout (conflict-free) ----
    float xv[4 * NCH];
    #pragma unroll
    for (int c = 0; c < NCH; ++c) {
        float4 v = s4[swz(4 * tid + c)];
        xv[4 * c + 0] = v.x; xv[4 * c + 1] = v.y;
        xv[4 * c + 2] = v.z; xv[4 * c + 3] = v.w;
    }

    float acc[RPT];
    #pragma unroll
    for (int r = 0; r < RPT; ++r) acc[r] = bval;

    #pragma unroll
    for (int k = 0; k < KK; ++k) {
        #pragma unroll
        for (int r = 0; r < RPT; ++r) {
            acc[r] = fmaf(xv[r + 1 + k], w[k], acc[r]);
        }
    }

    float* orow = out + (size_t)row * TT + a;
    #pragma unroll
    for (int c = 0; c < RPT / 4; ++c) {
        *reinterpret_cast<float4*>(orow + 4 * c) =
            make_float4(acc[4 * c], acc[4 * c + 1], acc[4 * c + 2], acc[4 * c + 3]);
    }
}

extern "C" void kernel_launch(void* const* d_in, const int* in_sizes, int n_in,
                              void* d_out, int out_size, void* d_ws, size_t ws_size,
                              hipStream_t stream) {
    const float* inp    = (const float*)d_in[0];   // (B, C, T) fp32
    const float* weight = (const float*)d_in[1];   // (H, 1, K) fp32
    const float* bias   = (const float*)d_in[2];   // (H,) fp32
    float* out = (float*)d_out;

    const int rows = BB * CC;                      // 8192 = one block per row
    lwconv_main<<<rows, 256, 0, stream>>>(inp, weight, bias, out);
}